// Round 6
// baseline (873.586 us; speedup 1.0000x reference)
//
#include <hip/hip_runtime.h>
#include <hip/hip_cooperative_groups.h>
#include <cmath>

namespace cg = cooperative_groups;

typedef _Float16 hf;
typedef hf hf4 __attribute__((ext_vector_type(4)));

constexpr int S = 160;
constexpr int BATCH = 4;
constexpr int TPB = 256;

constexpr int KC = S / 4;           // 40 hf4/float4 chunks per row
constexpr int LPR = 8;              // lanes per row
constexpr int CPL = KC / LPR;       // 5 chunks per lane
constexpr int RPB = TPB / LPR;      // 32 rows per pass
constexpr int NZ = S / RPB;         // 5 (fallback consumer z)

// cooperative kernel geometry
constexpr int CR = 80;              // rows per coop block (z in {0,1})
constexpr int CPASS = 3;            // passes: 32 + 32 + 16 rows
constexpr int SIBP = 164;           // padded LDS row stride in hf (bank spread)

// fp32 fallback geometry (r1 kernel, proven)
constexpr int FZSPLIT = 2;
constexpr int FROWS = S / FZSPLIT;
constexpr int FKC = S / 4;
constexpr int FLPR = 8;
constexpr int FCPL = FKC / FLPR;
constexpr int FRPP = TPB / FLPR;
constexpr int FPASSES = (FROWS + FRPP - 1) / FRPP;

__device__ __forceinline__ float sigmoidf_(float x) {
  return 1.0f / (1.0f + expf(-x));
}

// wf[b][h][t] = (mask[b][t][h] != 0 && t != h) ? 1 : 0   (byte)
__global__ void prep_wf(const int* __restrict__ mask, unsigned char* __restrict__ wf) {
  int i = blockIdx.x * blockDim.x + threadIdx.x;
  if (i >= BATCH * S * S) return;
  int t = i % S;
  int bh = i / S;
  int h = bh % S;
  int b = bh / S;
  wf[i] = (mask[(b * S + t) * S + h] != 0 && t != h) ? 1 : 0;
}

// All 3 MFVI iterations in ONE cooperative kernel. Block (m,b,z) owns 80 rows.
// Phase 0 reads fp32 tensors once; masked fp16 copies are retained on-chip:
// sib -> LDS (25.6 KB), cop -> 15 hf4 registers, grd -> fp16 workspace (L3).
// grid.sync() between iterations; q1 re-reads are L2-resident (400 KB actual).
__global__ __launch_bounds__(TPB, 5) void mfvi_coop(
    const float* __restrict__ s_edge,   // [b][m][h]
    const float* __restrict__ s_sib,    // [b][m][h][t]
    const float* __restrict__ s_cop,
    const float* __restrict__ s_grd,
    const int* __restrict__ mask,       // [b][x][y]
    const unsigned char* __restrict__ wf,  // [b][h][t]
    hf* __restrict__ Gw,                // masked grd fp16 [b][m][h][t]
    float* __restrict__ q1B, float* __restrict__ q1Bt,
    float* __restrict__ q1A, float* __restrict__ q1At,
    float* __restrict__ outp) {         // [b][m][h][2]
  cg::grid_group grid = cg::this_grid();
  const int m = blockIdx.x;
  const int b = blockIdx.y;
  const int z = blockIdx.z;
  const int tid = threadIdx.x;
  const int r0 = tid >> 3;
  const int j = tid & 7;
  const size_t bm = (size_t)b * S + m;
  const int h0 = z * CR;

  __shared__ __align__(16) hf sibL[CR][SIBP];   // 26.2 KB
  __shared__ __align__(16) float colm[S];
  __shared__ __align__(16) float rowm[S];
  __shared__ float sef[CR];
  __shared__ float pmf[CR];

  if (tid < CR) {
    sef[tid] = s_edge[bm * S + h0 + tid];
    pmf[tid] = (mask[bm * S + h0 + tid] != 0) ? 1.0f : 0.0f;
  }
  __syncthreads();

  const int msel = m >> 2;
  const unsigned mclr = ~(255u << ((m & 3) * 8));

  hf4 copReg[CPASS * CPL];   // statically indexed only -> stays in VGPRs

  // ---------- phase 0: iteration 1 (q1 == 0.5 analytic) + build copies ----
#pragma unroll
  for (int p = 0; p < CPASS; ++p) {
    const int r = p * RPB + r0;
    if (r < CR) {
      const int h = h0 + r;
      const float pm = pmf[r];
      const size_t rowf = (bm * S + h) * (size_t)S;
      const float4* SSr = (const float4*)(s_sib + rowf);
      const float4* CCr = (const float4*)(s_cop + rowf);
      const float4* GGr = (const float4*)(s_grd + rowf);
      const unsigned* WFr = (const unsigned*)(wf + ((size_t)b * S + h) * S);
      hf* Gr = Gw + rowf;
      float acc = 0.0f;
#pragma unroll
      for (int i = 0; i < CPL; ++i) {
        const int k = j + i * LPR;
        unsigned wu = WFr[k];
        float4 s = SSr[k];
        float4 cv = CCr[k];
        float4 gv = GGr[k];
        if (k == msel) wu &= mclr;   // fold t != m
        const float w0 = (float)(wu & 255u) * pm;
        const float w1 = (float)((wu >> 8) & 255u) * pm;
        const float w2 = (float)((wu >> 16) & 255u) * pm;
        const float w3 = (float)(wu >> 24) * pm;
        const float a0 = w0 * s.x, a1 = w1 * s.y, a2 = w2 * s.z, a3 = w3 * s.w;
        const float d0 = w0 * cv.x, d1 = w1 * cv.y, d2 = w2 * cv.z, d3 = w3 * cv.w;
        const float e0 = w0 * gv.x, e1 = w1 * gv.y, e2 = w2 * gv.z, e3 = w3 * gv.w;
        acc += ((a0 + d0 + e0) + (a1 + d1 + e1)) +
               ((a2 + d2 + e2) + (a3 + d3 + e3));
        hf4 A = {(hf)a0, (hf)a1, (hf)a2, (hf)a3};
        hf4 D = {(hf)d0, (hf)d1, (hf)d2, (hf)d3};
        hf4 E = {(hf)e0, (hf)e1, (hf)e2, (hf)e3};
        *(hf4*)(&sibL[r][4 * k]) = A;
        copReg[p * CPL + i] = D;
        *(hf4*)(Gr + 4 * k) = E;
      }
      acc += __shfl_xor(acc, 1);
      acc += __shfl_xor(acc, 2);
      acc += __shfl_xor(acc, 4);
      if (j == 0) {
        const float qv = fmaf(0.5f, acc, sef[r]);   // pm folded into acc
        const float sg = sigmoidf_(qv);
        q1B[((size_t)b * S + h) * S + m] = sg;
        q1Bt[bm * S + h] = sg;
      }
    }
  }
  __threadfence();
  grid.sync();

  // ---------- phases 1,2: iterations 2,3 from on-chip copies ----
#pragma unroll
  for (int it = 0; it < 2; ++it) {
    const bool last = (it == 1);
    const float* qin = last ? q1A : q1B;     // [b][x][y]
    const float* qint = last ? q1At : q1Bt;  // [b][y][x]
    if (tid < S) {
      colm[tid] = qint[bm * S + tid];   // q1[t, m]
      rowm[tid] = qin[bm * S + tid];    // q1[m, t]
    }
    __syncthreads();
#pragma unroll
    for (int p = 0; p < CPASS; ++p) {
      const int r = p * RPB + r0;
      if (r < CR) {
        const int h = h0 + r;
        const float4* Qr = (const float4*)(qin + ((size_t)b * S + h) * (size_t)S);
        const hf* Gr = Gw + (bm * S + h) * (size_t)S;
        float accA = 0.0f, accB = 0.0f, accC = 0.0f;
#pragma unroll
        for (int i = 0; i < CPL; ++i) {
          const int k = j + i * LPR;
          float4 q = Qr[k];
          float4 cm = ((const float4*)colm)[k];
          float4 rm = ((const float4*)rowm)[k];
          hf4 A = *(const hf4*)(&sibL[r][4 * k]);
          hf4 D = copReg[p * CPL + i];
          hf4 E = *(const hf4*)(Gr + 4 * k);
          accA = fmaf(q.x, (float)A[0], accA);
          accA = fmaf(q.y, (float)A[1], accA);
          accA = fmaf(q.z, (float)A[2], accA);
          accA = fmaf(q.w, (float)A[3], accA);
          accB = fmaf(cm.x, (float)D[0], accB);
          accB = fmaf(cm.y, (float)D[1], accB);
          accB = fmaf(cm.z, (float)D[2], accB);
          accB = fmaf(cm.w, (float)D[3], accB);
          accC = fmaf(rm.x, (float)E[0], accC);
          accC = fmaf(rm.y, (float)E[1], accC);
          accC = fmaf(rm.z, (float)E[2], accC);
          accC = fmaf(rm.w, (float)E[3], accC);
        }
        float acc = accA + accB + accC;
        acc += __shfl_xor(acc, 1);
        acc += __shfl_xor(acc, 2);
        acc += __shfl_xor(acc, 4);
        if (j == 0) {
          const float qv = sef[r] + acc;
          if (!last) {
            const float sg = sigmoidf_(qv);
            q1A[((size_t)b * S + h) * S + m] = sg;
            q1At[bm * S + h] = sg;
          } else {
            float2 o;
            o.x = sigmoidf_(-qv);
            o.y = sigmoidf_(qv);
            ((float2*)outp)[bm * S + h] = o;
          }
        }
      }
    }
    if (!last) {
      __threadfence();
      grid.sync();
    }
  }
}

// ---------------- fallback (proven r4 fp16 3-dispatch path) ----------------
__global__ __launch_bounds__(TPB) void mfvi_first(
    const float* __restrict__ s_edge, const float* __restrict__ s_sib,
    const float* __restrict__ s_cop, const float* __restrict__ s_grd,
    const int* __restrict__ mask, const unsigned char* __restrict__ wf,
    hf* __restrict__ Aw, hf* __restrict__ Bw, hf* __restrict__ Cw,
    float* __restrict__ q1_out, float* __restrict__ q1t_out) {
  const int m = blockIdx.x;
  const int b = blockIdx.y;
  const int z = blockIdx.z;
  const int tid = threadIdx.x;

  __shared__ float sef[RPB];
  __shared__ float pmf[RPB];

  const size_t bm = (size_t)b * S + m;
  const int h0 = z * RPB;

  if (tid < RPB) {
    sef[tid] = s_edge[bm * S + h0 + tid];
    pmf[tid] = (mask[bm * S + h0 + tid] != 0) ? 1.0f : 0.0f;
  }
  __syncthreads();

  const int r = tid >> 3;
  const int j = tid & 7;
  const int h = h0 + r;

  const size_t rowf = (bm * S + h) * (size_t)S;
  const float4* SSr = (const float4*)(s_sib + rowf);
  const float4* CCr = (const float4*)(s_cop + rowf);
  const float4* GGr = (const float4*)(s_grd + rowf);
  const unsigned* WFr = (const unsigned*)(wf + ((size_t)b * S + h) * S);
  hf* Ar = Aw + rowf;
  hf* Br = Bw + rowf;
  hf* Cr = Cw + rowf;

  const int msel = m >> 2;
  const unsigned mclr = ~(255u << ((m & 3) * 8));
  const float pm = pmf[r];

  float accA = 0.0f, accB = 0.0f, accC = 0.0f;
#pragma unroll
  for (int i = 0; i < CPL; ++i) {
    const int k = j + i * LPR;
    unsigned wu = WFr[k];
    float4 s = SSr[k];
    float4 cv = CCr[k];
    float4 gv = GGr[k];
    if (k == msel) wu &= mclr;
    const float w0 = (float)(wu & 255u) * pm;
    const float w1 = (float)((wu >> 8) & 255u) * pm;
    const float w2 = (float)((wu >> 16) & 255u) * pm;
    const float w3 = (float)(wu >> 24) * pm;
    const float a0 = w0 * s.x, a1 = w1 * s.y, a2 = w2 * s.z, a3 = w3 * s.w;
    const float b0 = w0 * cv.x, b1 = w1 * cv.y, b2 = w2 * cv.z, b3 = w3 * cv.w;
    const float e0 = w0 * gv.x, e1 = w1 * gv.y, e2 = w2 * gv.z, e3 = w3 * gv.w;
    accA += (a0 + a1) + (a2 + a3);
    accB += (b0 + b1) + (b2 + b3);
    accC += (e0 + e1) + (e2 + e3);
    hf4 A = {(hf)a0, (hf)a1, (hf)a2, (hf)a3};
    hf4 B = {(hf)b0, (hf)b1, (hf)b2, (hf)b3};
    hf4 C = {(hf)e0, (hf)e1, (hf)e2, (hf)e3};
    *(hf4*)(Ar + 4 * k) = A;
    *(hf4*)(Br + 4 * k) = B;
    *(hf4*)(Cr + 4 * k) = C;
  }
  float acc = accA + accB + accC;
  acc += __shfl_xor(acc, 1);
  acc += __shfl_xor(acc, 2);
  acc += __shfl_xor(acc, 4);
  if (j == 0) {
    const float qv = fmaf(0.5f, acc, sef[r]);
    const float sg1 = sigmoidf_(qv);
    q1_out[((size_t)b * S + h) * S + m] = sg1;
    q1t_out[bm * S + h] = sg1;
  }
}

template <bool LAST>
__global__ __launch_bounds__(TPB) void mfvi_next(
    const float* __restrict__ s_edge,
    const hf* __restrict__ Aw, const hf* __restrict__ Bw, const hf* __restrict__ Cw,
    const float* __restrict__ q1_in, const float* __restrict__ q1t_in,
    float* __restrict__ q1_out, float* __restrict__ q1t_out,
    float* __restrict__ outp) {
  const int m = blockIdx.x;
  const int b = blockIdx.y;
  const int z = blockIdx.z;
  const int tid = threadIdx.x;

  __shared__ __align__(16) float colm[S];
  __shared__ __align__(16) float rowm[S];
  __shared__ float sef[RPB];

  const size_t bm = (size_t)b * S + m;
  const int h0 = z * RPB;

  if (tid < S) {
    colm[tid] = q1t_in[bm * S + tid];
    rowm[tid] = q1_in[bm * S + tid];
    if (tid < RPB) sef[tid] = s_edge[bm * S + h0 + tid];
  }
  __syncthreads();

  const int r = tid >> 3;
  const int j = tid & 7;
  const int h = h0 + r;

  const size_t rowf = (bm * S + h) * (size_t)S;
  const hf* Ar = Aw + rowf;
  const hf* Br = Bw + rowf;
  const hf* Cr = Cw + rowf;
  const float4* Qr = (const float4*)(q1_in + ((size_t)b * S + h) * (size_t)S);

  float accA = 0.0f, accB = 0.0f, accC = 0.0f;
#pragma unroll
  for (int i = 0; i < CPL; ++i) {
    const int k = j + i * LPR;
    hf4 A = *(const hf4*)(Ar + 4 * k);
    hf4 B = *(const hf4*)(Br + 4 * k);
    hf4 C = *(const hf4*)(Cr + 4 * k);
    float4 q = Qr[k];
    const float4 cm = ((const float4*)colm)[k];
    const float4 rm = ((const float4*)rowm)[k];
    accA = fmaf(q.x, (float)A[0], accA);
    accA = fmaf(q.y, (float)A[1], accA);
    accA = fmaf(q.z, (float)A[2], accA);
    accA = fmaf(q.w, (float)A[3], accA);
    accB = fmaf(cm.x, (float)B[0], accB);
    accB = fmaf(cm.y, (float)B[1], accB);
    accB = fmaf(cm.z, (float)B[2], accB);
    accB = fmaf(cm.w, (float)B[3], accB);
    accC = fmaf(rm.x, (float)C[0], accC);
    accC = fmaf(rm.y, (float)C[1], accC);
    accC = fmaf(rm.z, (float)C[2], accC);
    accC = fmaf(rm.w, (float)C[3], accC);
  }
  float acc = accA + accB + accC;
  acc += __shfl_xor(acc, 1);
  acc += __shfl_xor(acc, 2);
  acc += __shfl_xor(acc, 4);
  if (j == 0) {
    const float qv = sef[r] + acc;
    if (!LAST) {
      const float sg1 = sigmoidf_(qv);
      q1_out[((size_t)b * S + h) * S + m] = sg1;
      q1t_out[bm * S + h] = sg1;
    } else {
      float2 o;
      o.x = sigmoidf_(-qv);
      o.y = sigmoidf_(qv);
      ((float2*)outp)[bm * S + h] = o;
    }
  }
}

// ---------------- fp32 fallback (r1 kernel, proven) ----------------
template <bool FIRST, bool LAST>
__global__ __launch_bounds__(TPB, 4) void mfvi_iter(
    const float* __restrict__ s_edge, const float* __restrict__ s_sib,
    const float* __restrict__ s_cop, const float* __restrict__ s_grd,
    const int* __restrict__ mask, const unsigned char* __restrict__ wf,
    const float* __restrict__ q1_in, float* __restrict__ q1_out,
    float* __restrict__ outp) {
  const int m = blockIdx.x;
  const int b = blockIdx.y;
  const int z = blockIdx.z;
  const int tid = threadIdx.x;

  __shared__ __align__(16) float colm[S];
  __shared__ __align__(16) float rowm[S];
  __shared__ float sef[FROWS];
  __shared__ float pmf[FROWS];

  const float* G = q1_in + (size_t)b * S * S;
  const size_t bm = (size_t)b * S + m;
  const int h0 = z * FROWS;

  if (tid < S) {
    if (!FIRST) {
      colm[tid] = G[tid * S + m];
      rowm[tid] = G[m * S + tid];
    }
    if (tid < FROWS) {
      sef[tid] = s_edge[bm * S + h0 + tid];
      pmf[tid] = (mask[bm * S + h0 + tid] != 0) ? 1.0f : 0.0f;
    }
  }
  __syncthreads();

  const size_t blk = (bm * S + h0) * (size_t)S;
  const float4* SS = (const float4*)(s_sib + blk);
  const float4* CC = (const float4*)(s_cop + blk);
  const float4* GG = (const float4*)(s_grd + blk);
  const float4* QQ = (const float4*)(G + h0 * S);
  const unsigned* WF = (const unsigned*)(wf + ((size_t)b * S + h0) * S);
  const int msel = m >> 2;
  const unsigned mclr = ~(255u << ((m & 3) * 8));

  const int g = tid >> 3;
  const int j = tid & 7;

#pragma unroll
  for (int p = 0; p < FPASSES; ++p) {
    const int r = p * FRPP + g;
    if (r < FROWS) {
      const int rowbase = r * FKC;
      float acc = 0.0f;
#pragma unroll
      for (int i = 0; i < FCPL; ++i) {
        const int k = j + i * FLPR;
        const int c = rowbase + k;
        unsigned wu = WF[c];
        float4 s = SS[c];
        float4 cv = CC[c];
        float4 gv = GG[c];
        if (k == msel) wu &= mclr;
        float w0 = (float)(wu & 255u);
        float w1 = (float)((wu >> 8) & 255u);
        float w2 = (float)((wu >> 16) & 255u);
        float w3 = (float)(wu >> 24);
        if (FIRST) {
          float t0 = s.x + cv.x + gv.x;
          float t1 = s.y + cv.y + gv.y;
          float t2 = s.z + cv.z + gv.z;
          float t3 = s.w + cv.w + gv.w;
          acc = fmaf(w0, t0, fmaf(w1, t1, fmaf(w2, t2, fmaf(w3, t3, acc))));
        } else {
          float4 q = QQ[c];
          float4 cm = ((const float4*)colm)[k];
          float4 rm = ((const float4*)rowm)[k];
          float t0 = fmaf(q.x, s.x, fmaf(cm.x, cv.x, rm.x * gv.x));
          float t1 = fmaf(q.y, s.y, fmaf(cm.y, cv.y, rm.y * gv.y));
          float t2 = fmaf(q.z, s.z, fmaf(cm.z, cv.z, rm.z * gv.z));
          float t3 = fmaf(q.w, s.w, fmaf(cm.w, cv.w, rm.w * gv.w));
          acc = fmaf(w0, t0, fmaf(w1, t1, fmaf(w2, t2, fmaf(w3, t3, acc))));
        }
      }
      acc += __shfl_xor(acc, 1);
      acc += __shfl_xor(acc, 2);
      acc += __shfl_xor(acc, 4);
      if (j == 0) {
        const int h = h0 + r;
        const float qv = fmaf(pmf[r], FIRST ? 0.5f * acc : acc, sef[r]);
        if (!LAST) {
          q1_out[((size_t)b * S + h) * S + m] = sigmoidf_(qv);
        } else {
          float2 o;
          o.x = sigmoidf_(-qv);
          o.y = sigmoidf_(qv);
          ((float2*)outp)[bm * S + h] = o;
        }
      }
    }
  }
}

extern "C" void kernel_launch(void* const* d_in, const int* in_sizes, int n_in,
                              void* d_out, int out_size, void* d_ws, size_t ws_size,
                              hipStream_t stream) {
  const float* s_edge = (const float*)d_in[0];
  const float* s_sib = (const float*)d_in[1];
  const float* s_cop = (const float*)d_in[2];
  const float* s_grd = (const float*)d_in[3];
  const int* mask = (const int*)d_in[4];
  float* outp = (float*)d_out;

  const int qn = BATCH * S * S;                      // 102,400
  const size_t NS3 = (size_t)BATCH * S * S * S;      // 16,384,000 elements
  const size_t need = 3 * NS3 * sizeof(hf) + 4 * (size_t)qn * sizeof(float) + qn;

  if (ws_size >= need) {
    hf* Aw = (hf*)d_ws;
    hf* Bw = Aw + NS3;
    hf* Cw = Bw + NS3;                               // coop uses Cw as Gw
    float* q1B = (float*)(Cw + NS3);
    float* q1Bt = q1B + qn;
    float* q1A = q1Bt + qn;
    float* q1At = q1A + qn;
    unsigned char* wf = (unsigned char*)(q1At + qn);

    prep_wf<<<(qn + 255) / 256, 256, 0, stream>>>(mask, wf);

    // try the single cooperative kernel first
    void* args[] = {
        (void*)&s_edge, (void*)&s_sib, (void*)&s_cop, (void*)&s_grd,
        (void*)&mask,   (void*)&wf,    (void*)&Cw,
        (void*)&q1B,    (void*)&q1Bt,  (void*)&q1A,   (void*)&q1At,
        (void*)&outp};
    hipError_t e = hipLaunchCooperativeKernel(
        (const void*)mfvi_coop, dim3(S, BATCH, 2), dim3(TPB, 1, 1), args, 0,
        stream);
    if (e != hipSuccess) {
      (void)hipGetLastError();  // clear error state; run proven 3-dispatch path
      dim3 grid(S, BATCH, NZ);
      mfvi_first<<<grid, TPB, 0, stream>>>(
          s_edge, s_sib, s_cop, s_grd, mask, wf, Aw, Bw, Cw, q1B, q1Bt);
      mfvi_next<false><<<grid, TPB, 0, stream>>>(
          s_edge, Aw, Bw, Cw, q1B, q1Bt, q1A, q1At, nullptr);
      mfvi_next<true><<<grid, TPB, 0, stream>>>(
          s_edge, Aw, Bw, Cw, q1A, q1At, nullptr, nullptr, outp);
    }
  } else {
    // fp32 fallback
    float* q1A = (float*)d_ws;
    float* q1B = q1A + qn;
    unsigned char* wf = (unsigned char*)(q1B + qn);

    prep_wf<<<(qn + 255) / 256, 256, 0, stream>>>(mask, wf);

    dim3 grid(S, BATCH, FZSPLIT);
    mfvi_iter<true, false><<<grid, TPB, 0, stream>>>(
        s_edge, s_sib, s_cop, s_grd, mask, wf, q1A, q1B, nullptr);
    mfvi_iter<false, false><<<grid, TPB, 0, stream>>>(
        s_edge, s_sib, s_cop, s_grd, mask, wf, q1B, q1A, nullptr);
    mfvi_iter<false, true><<<grid, TPB, 0, stream>>>(
        s_edge, s_sib, s_cop, s_grd, mask, wf, q1A, nullptr, outp);
  }
}